// Round 17
// baseline (284.717 us; speedup 1.0000x reference)
//
#include <hip/hip_runtime.h>
#include <math.h>

#define NTOT   131072        // B * NPG
#define NPG    2048
#define NB     64
#define KNNK   10
#define HID    64
#define EPSPN  1e-5f

__device__ inline float rdlane(float v, int l) {
    return __int_as_float(__builtin_amdgcn_readlane(__float_as_int(v), l));
}

typedef short v8bf  __attribute__((ext_vector_type(8)));   // 8 bf16 = 4 VGPRs
typedef float v16f  __attribute__((ext_vector_type(16)));  // MFMA 32x32 acc

__device__ inline unsigned short f2bf(float f) {           // RNE f32->bf16
    unsigned u = __float_as_uint(f);
    return (unsigned short)((u + 0x7FFFu + ((u >> 16) & 1u)) >> 16);
}
__device__ inline float bf2f(unsigned short s) {
    return __uint_as_float((unsigned)s << 16);
}
__device__ inline void split_bf(float v, short& hi, short& lo) {
    unsigned short h = f2bf(v);
    hi = (short)h;
    lo = (short)f2bf(v - bf2f(h));
}

// ---------------------------------------------------------------------------
// sort: per graph, bitonic sort by x -> spos, then bitonic sort of the
// x-sorted array by y -> y2x map. (R12-proven)
// ---------------------------------------------------------------------------
__global__ __launch_bounds__(1024) void sort_kernel(const float2* __restrict__ pos,
        float2* __restrict__ spos, unsigned short* __restrict__ y2xg)
{
    __shared__ float2   sp[NPG];
    __shared__ unsigned sk[NPG];
    __shared__ unsigned sv[NPG];
    const int base = blockIdx.x * NPG;
    const int tid  = threadIdx.x;

    for (int t = tid; t < NPG; t += 1024) {
        unsigned u = __float_as_uint(pos[base + t].x);
        sk[t] = (u & 0x80000000u) ? ~u : (u | 0x80000000u);
        sv[t] = (unsigned)t;
    }
    __syncthreads();
    for (int k = 2; k <= NPG; k <<= 1) {
        for (int j = k >> 1; j > 0; j >>= 1) {
            int i = ((tid & ~(j - 1)) << 1) | (tid & (j - 1));
            int l = i + j;
            bool up = ((i & k) == 0);
            unsigned a = sk[i], b = sk[l];
            if ((a > b) == up) {
                sk[i] = b; sk[l] = a;
                unsigned t2 = sv[i]; sv[i] = sv[l]; sv[l] = t2;
            }
            __syncthreads();
        }
    }
    for (int t = tid; t < NPG; t += 1024) sp[t] = pos[base + sv[t]];
    __syncthreads();
    for (int t = tid; t < NPG; t += 1024) spos[base + t] = sp[t];

    for (int t = tid; t < NPG; t += 1024) {
        unsigned u = __float_as_uint(sp[t].y);
        sk[t] = (u & 0x80000000u) ? ~u : (u | 0x80000000u);
        sv[t] = (unsigned)t;                 // val = x-rank
    }
    __syncthreads();
    for (int k = 2; k <= NPG; k <<= 1) {
        for (int j = k >> 1; j > 0; j >>= 1) {
            int i = ((tid & ~(j - 1)) << 1) | (tid & (j - 1));
            int l = i + j;
            bool up = ((i & k) == 0);
            unsigned a = sk[i], b = sk[l];
            if ((a > b) == up) {
                sk[i] = b; sk[l] = a;
                unsigned t2 = sv[i]; sv[i] = sv[l]; sv[l] = t2;
            }
            __syncthreads();
        }
    }
    for (int t = tid; t < NPG; t += 1024) y2xg[base + t] = (unsigned short)sv[t];
}

// ---------------------------------------------------------------------------
// knn: R16 structure (2 lanes/query, 24KB LDS, batch-4, pair prune,
// bitonic pair-merge) with PER-CANDIDATE insert ballots: each of the 4
// candidates gets its own __any gate, so one straggler candidate costs one
// 54-VALU ladder instead of four.
// ---------------------------------------------------------------------------
#define INSERT(INS, D2, JJ) do {                                              \
    const bool ins_ = (INS);                                                  \
    bd[9] = ins_ ? (D2) : bd[9];                                              \
    bi[9] = ins_ ? (JJ) : bi[9];                                              \
    _Pragma("unroll")                                                         \
    for (int kk = 0; kk < 9; ++kk) {                                          \
        bool sw_ = bd[kk] > bd[9];                                            \
        float tv_ = bd[kk]; int ti_ = bi[kk];                                 \
        bd[kk] = sw_ ? bd[9] : bd[kk]; bi[kk] = sw_ ? bi[9] : bi[kk];         \
        bd[9]  = sw_ ? tv_  : bd[9];   bi[9]  = sw_ ? ti_  : bi[9];           \
    }                                                                         \
} while (0)

#define CSWAP(A, B) do {                                                      \
    bool sw_ = bd[A] > bd[B];                                                 \
    float tf_ = bd[A]; int ti_ = bi[A];                                       \
    bd[A] = sw_ ? bd[B] : bd[A]; bi[A] = sw_ ? bi[B] : bi[A];                 \
    bd[B] = sw_ ? tf_  : bd[B]; bi[B] = sw_ ? ti_  : bi[B];                   \
} while (0)

__global__ __launch_bounds__(256) void knn_kernel(const float2* __restrict__ spos,
        const unsigned short* __restrict__ y2xg, unsigned short* __restrict__ knn)
{
    __shared__ float2 sarr[NPG];            // x-sorted positions (16KB)
    __shared__ unsigned short y2x[NPG];     // y-rank -> x-rank (4KB)
    __shared__ unsigned short x2y[NPG];     // x-rank -> y-rank (4KB)
    const int tid  = threadIdx.x;
    const int g    = blockIdx.x >> 4;
    const int base = g * NPG;

    for (int t = tid; t < NPG; t += 256) {
        sarr[t] = spos[base + t];
        y2x[t]  = y2xg[base + t];
    }
    __syncthreads();
    for (int t = tid; t < NPG; t += 256) {
        x2y[(int)y2x[t]] = (unsigned short)t;
    }
    __syncthreads();

    const int ql = ((blockIdx.x & 15) << 7) + (tid >> 1);   // query x-rank
    const int d  = tid & 1;
    const float qx = sarr[ql].x, qy = sarr[ql].y;
    const int py = (int)x2y[ql];

    float span_x = sarr[min(ql + 8, NPG - 1)].x - sarr[max(ql - 8, 0)].x;
    float span_y = sarr[(int)y2x[min(py + 8, NPG - 1)]].y
                 - sarr[(int)y2x[max(py - 8, 0)]].y;
    const bool cy   = span_y > span_x;
    const int  r    = cy ? py : ql;
    const int  limit = d ? (NPG - 1 - r) : r;
    const int  sign  = d ? 1 : -1;

    float bd[KNNK];
    int   bi[KNNK];
#pragma unroll
    for (int k = 0; k < KNNK; ++k) { bd[k] = INFINITY; bi[k] = 0; }

    int s = 1;
    bool alive = (limit >= 1);
    while (__any(alive)) {
        int j0 = min(NPG - 1, max(0, r + sign * s));
        int j1 = min(NPG - 1, max(0, r + sign * (s + 1)));
        int j2 = min(NPG - 1, max(0, r + sign * (s + 2)));
        int j3 = min(NPG - 1, max(0, r + sign * (s + 3)));
        int x0 = cy ? (int)y2x[j0] : j0;
        int x1 = cy ? (int)y2x[j1] : j1;
        int x2 = cy ? (int)y2x[j2] : j2;
        int x3 = cy ? (int)y2x[j3] : j3;
        float2 p0 = sarr[x0];
        float2 p1 = sarr[x1];
        float2 p2 = sarr[x2];
        float2 p3 = sarr[x3];
        float dx0 = __fsub_rn(qx, p0.x), dy0 = __fsub_rn(qy, p0.y);
        float dx1 = __fsub_rn(qx, p1.x), dy1 = __fsub_rn(qy, p1.y);
        float dx2 = __fsub_rn(qx, p2.x), dy2 = __fsub_rn(qy, p2.y);
        float dx3 = __fsub_rn(qx, p3.x), dy3 = __fsub_rn(qy, p3.y);
        float xs0 = __fmul_rn(dx0, dx0), ys0 = __fmul_rn(dy0, dy0);
        float xs1 = __fmul_rn(dx1, dx1), ys1 = __fmul_rn(dy1, dy1);
        float xs2 = __fmul_rn(dx2, dx2), ys2 = __fmul_rn(dy2, dy2);
        float xs3 = __fmul_rn(dx3, dx3), ys3 = __fmul_rn(dy3, dy3);
        float d20 = __fadd_rn(xs0, ys0);
        float d21 = __fadd_rn(xs1, ys1);
        float d22 = __fadd_rn(xs2, ys2);
        float d23 = __fadd_rn(xs3, ys3);
        bool v0 = alive && (s     <= limit);
        bool v1 = alive && (s + 1 <= limit);
        bool v2 = alive && (s + 2 <= limit);
        bool v3 = alive && (s + 3 <= limit);
        // per-candidate ballots: bd[9] updates between tests
        bool c0 = v0 && (d20 < bd[9]);
        if (__any(c0)) INSERT(c0, d20, x0);
        bool c1 = v1 && (d21 < bd[9]);
        if (__any(c1)) INSERT(c1, d21, x1);
        bool c2 = v2 && (d22 < bd[9]);
        if (__any(c2)) INSERT(c2, d22, x2);
        bool c3 = v3 && (d23 < bd[9]);
        if (__any(c3)) INSERT(c3, d23, x3);

        float thr = fminf(bd[9], __shfl_xor(bd[9], 1));
        float pr3 = cy ? ys3 : xs3;
        alive = alive && (s + 4 <= limit) && (pr3 < thr);
        s += 4;
    }

#pragma unroll
    for (int ph = 0; ph < 10; ++ph) {
        if ((ph & 1) == 0) { CSWAP(0,1); CSWAP(2,3); CSWAP(4,5); CSWAP(6,7); CSWAP(8,9); }
        else               { CSWAP(1,2); CSWAP(3,4); CSWAP(5,6); CSWAP(7,8); }
    }
    float obd[KNNK]; int obi[KNNK];
#pragma unroll
    for (int k = 0; k < KNNK; ++k) {
        obd[k] = __shfl_xor(bd[k], 1);
        obi[k] = __shfl_xor(bi[k], 1);
    }
    if (d == 0) {
        const int row = (base + ql) * KNNK;
#pragma unroll
        for (int k = 0; k < KNNK; ++k) {
            bool ta = bd[k] < obd[9 - k];
            int idx = ta ? bi[k] : obi[9 - k];     // local x-rank
            knn[row + k] = (unsigned short)idx;
        }
    }
}

// ---------------------------------------------------------------------------
// MFMA gemm epilogue (split-bf16, R8/R14-verified numerics).
// Layouts (32x32x16 bf16): A: lane holds A[l&31][8*(l>>5)+j];
// B: B[8*(l>>5)+j][l&31]; C/D: row=(reg&3)+8*(reg>>2)+4*(l>>5), col=l&31.
// ---------------------------------------------------------------------------
__device__ inline void build_bfrags(const float* __restrict__ Wa, int lane,
                                    v8bf (&bhi)[4][2], v8bf (&blo)[4][2])
{
    const int cl = lane & 31, kg = lane >> 5;
#pragma unroll
    for (int kt = 0; kt < 4; ++kt)
#pragma unroll
        for (int nt = 0; nt < 2; ++nt)
#pragma unroll
            for (int j = 0; j < 8; ++j) {
                float wv = Wa[(kt * 16 + kg * 8 + j) * HID + nt * 32 + cl];
                short h, l;
                split_bf(wv, h, l);
                bhi[kt][nt][j] = h; blo[kt][nt][j] = l;
            }
}

__device__ inline void mfma_gemm_store(const float* vrow,
        const v8bf (&bhi)[4][2], const v8bf (&blo)[4][2],
        int lane, int i0, float* __restrict__ out)
{
    const int cl = lane & 31, kg = lane >> 5;
    v16f acc0, acc1;
#pragma unroll
    for (int q = 0; q < 16; ++q) { acc0[q] = 0.f; acc1[q] = 0.f; }
#pragma unroll
    for (int kt = 0; kt < 4; ++kt) {
        const float4 f0 = *(const float4*)(vrow + cl * 68 + kt * 16 + kg * 8);
        const float4 f1 = *(const float4*)(vrow + cl * 68 + kt * 16 + kg * 8 + 4);
        v8bf ah, al;
        short h, l;
        split_bf(f0.x, h, l); ah[0] = h; al[0] = l;
        split_bf(f0.y, h, l); ah[1] = h; al[1] = l;
        split_bf(f0.z, h, l); ah[2] = h; al[2] = l;
        split_bf(f0.w, h, l); ah[3] = h; al[3] = l;
        split_bf(f1.x, h, l); ah[4] = h; al[4] = l;
        split_bf(f1.y, h, l); ah[5] = h; al[5] = l;
        split_bf(f1.z, h, l); ah[6] = h; al[6] = l;
        split_bf(f1.w, h, l); ah[7] = h; al[7] = l;
        acc0 = __builtin_amdgcn_mfma_f32_32x32x16_bf16(ah, bhi[kt][0], acc0, 0, 0, 0);
        acc0 = __builtin_amdgcn_mfma_f32_32x32x16_bf16(al, bhi[kt][0], acc0, 0, 0, 0);
        acc0 = __builtin_amdgcn_mfma_f32_32x32x16_bf16(ah, blo[kt][0], acc0, 0, 0, 0);
        acc1 = __builtin_amdgcn_mfma_f32_32x32x16_bf16(ah, bhi[kt][1], acc1, 0, 0, 0);
        acc1 = __builtin_amdgcn_mfma_f32_32x32x16_bf16(al, bhi[kt][1], acc1, 0, 0, 0);
        acc1 = __builtin_amdgcn_mfma_f32_32x32x16_bf16(ah, blo[kt][1], acc1, 0, 0, 0);
    }
#pragma unroll
    for (int reg = 0; reg < 16; ++reg) {
        int rowc = (reg & 3) + 8 * (reg >> 2) + 4 * kg;
        out[(size_t)(i0 + rowc) * HID + cl]      = acc0[reg];
        out[(size_t)(i0 + rowc) * HID + 32 + cl] = acc1[reg];
    }
}

// XCD-aware work swizzle for grid=1024 (8 whole graphs per XCD's L2).
#define WSWZ() (((blockIdx.x & 7) << 7) | (blockIdx.x >> 3))

// ---------------------------------------------------------------------------
// conv1: edge conv (pos from LDS, split fmax chain) + MFMA gemm(W2a)
// (b-frags built AFTER the loop) + fused PairNorm stats.
// ---------------------------------------------------------------------------
__global__ __launch_bounds__(256) void conv1_kernel(const float2* __restrict__ spos,
        const unsigned short* __restrict__ knn, const float* __restrict__ W1,
        const float* __restrict__ b1, const float* __restrict__ W2a,
        float* __restrict__ out, float* __restrict__ st)
{
    __shared__ float red[256];
    __shared__ float2 sarr[NPG];                       // 16KB
    __shared__ __align__(16) float vbuf[4][32 * 68];   // 34.8KB
    const int tid  = threadIdx.x;
    const int lane = tid & 63, w = tid >> 6;
    const int wg   = WSWZ();
    const int i0   = wg * 128 + w * 32;
    const int base = (wg >> 4) << 11;
    const int il0  = i0 - base;
    const float w0 = W1[lane], w1 = W1[HID + lane], bb = b1[lane];
    for (int t = tid; t < NPG; t += 256) sarr[t] = spos[base + t];
    __syncthreads();
    float cs = 0.f, ss = 0.f;
    for (int r = 0; r < 32; ++r) {
        const int il = il0 + r;
        float2 pi = sarr[il];
        float a0 = bb, a1 = bb;                      // self edge (rel = 0)
#pragma unroll
        for (int e = 0; e < 5; ++e) {
            int ja = (int)knn[(size_t)(base + il) * KNNK + 2 * e];
            int jb = (int)knn[(size_t)(base + il) * KNNK + 2 * e + 1];
            float2 pa = sarr[ja];
            float2 pb = sarr[jb];
            a0 = fmaxf(a0, fmaf(pa.x - pi.x, w0, fmaf(pa.y - pi.y, w1, bb)));
            a1 = fmaxf(a1, fmaf(pb.x - pi.x, w0, fmaf(pb.y - pi.y, w1, bb)));
        }
        float v = fmaxf(fmaxf(a0, a1), 0.f);
        cs += v; ss = fmaf(v, v, ss);
        vbuf[w][r * 68 + lane] = v;
    }
    v8bf bhi[4][2], blo[4][2];
    build_bfrags(W2a, lane, bhi, blo);
    mfma_gemm_store(vbuf[w], bhi, blo, lane, i0, out);

    red[tid] = cs; __syncthreads();
    if (tid < 64) atomicAdd(&st[tid], red[tid] + red[tid + 64] + red[tid + 128] + red[tid + 192]);
#pragma unroll
    for (int o = 32; o > 0; o >>= 1) ss += __shfl_xor(ss, o, 64);
    __syncthreads();
    if (lane == 0) red[w] = ss;
    __syncthreads();
    if (tid == 0) atomicAdd(&st[64], red[0] + red[1] + red[2] + red[3]);
}

// ---------------------------------------------------------------------------
// stats: mean, inv = 1/sqrt(eps + var-of-rows), offs = b_next - inv*mean@Wnext_a
// ---------------------------------------------------------------------------
__global__ __launch_bounds__(64) void stats_kernel(float* __restrict__ st,
        const float* __restrict__ Wn, const float* __restrict__ bn)
{
    const int c = threadIdx.x;
    float mean = st[c] * (1.0f / (float)NTOT);
    st[128 + c] = mean;
    float m2 = mean * mean;
#pragma unroll
    for (int o = 32; o > 0; o >>= 1) m2 += __shfl_xor(m2, o, 64);
    float s = (st[64] - (float)NTOT * m2) * (1.0f / (float)NTOT);
    s = fmaxf(s, 0.f);
    float inv = 1.0f / sqrtf(EPSPN + s);
    if (c == 0) st[66] = inv;
    if (Wn != nullptr) {
        float dot = 0.f;
#pragma unroll
        for (int k = 0; k < HID; ++k) dot = fmaf(rdlane(mean, k), Wn[k * HID + c], dot);
        st[192 + c] = bn[c] - inv * dot;
    }
}

// ---------------------------------------------------------------------------
// convG2: R16 1-deep pipelined gather conv (idx 2-ahead, hw 1-ahead) + LDS
// pos + self-hw prefetch + split fmax chain + MFMA gemm (frags after loop).
// ---------------------------------------------------------------------------
__global__ __launch_bounds__(256, 2) void convG2_kernel(const float2* __restrict__ spos,
        const unsigned short* __restrict__ knn, const float* __restrict__ hw,
        const float* __restrict__ Wb, const float* __restrict__ Wna,
        const float* __restrict__ stin, float* __restrict__ out,
        float* __restrict__ stout)
{
    __shared__ float red[256];
    __shared__ float2 sarr[NPG];
    __shared__ __align__(16) float vbuf[4][32 * 68];
    const int tid  = threadIdx.x;
    const int lane = tid & 63, w = tid >> 6;
    const int wg   = WSWZ();
    const int i0   = wg * 128 + w * 32;
    const int base = (wg >> 4) << 11;
    const float wb0 = Wb[lane], wb1 = Wb[HID + lane];
    const float inv = stin[66], offs = stin[192 + lane];
    for (int t = tid; t < NPG; t += 256) sarr[t] = spos[base + t];
    __syncthreads();

    const unsigned* kb = (const unsigned*)knn;
    unsigned idx0[5], idx1[5];
    float hwC[KNNK], hwN[KNNK], hwS, hwSN;
#pragma unroll
    for (int e = 0; e < 5; ++e) idx0[e] = kb[(size_t)i0 * 5 + e];
#pragma unroll
    for (int e = 0; e < 5; ++e) idx1[e] = kb[(size_t)(i0 + 1) * 5 + e];
#pragma unroll
    for (int e = 0; e < 5; ++e) {
        int ja = base + (int)(idx0[e] & 0xFFFFu);
        int jb = base + (int)(idx0[e] >> 16);
        hwC[2 * e]     = hw[(size_t)ja * HID + lane];
        hwC[2 * e + 1] = hw[(size_t)jb * HID + lane];
    }
    hwS = hw[(size_t)i0 * HID + lane];

    float cs = 0.f, ss = 0.f;
    for (int r = 0; r < 32; ++r) {
        const int i = i0 + r;
        const int il = i - base;
        unsigned idx2[5];
        if (r + 2 < 32) {
#pragma unroll
            for (int e = 0; e < 5; ++e) idx2[e] = kb[(size_t)(i + 2) * 5 + e];
        }
        float2 pi = sarr[il];
        float a0 = fmaf(inv, hwS, offs);             // self edge (prefetched)
        float a1 = -INFINITY;
#pragma unroll
        for (int e = 0; e < 5; ++e) {
            int la = (int)(idx0[e] & 0xFFFFu);
            int lb = (int)(idx0[e] >> 16);
            float2 pa = sarr[la];
            float2 pb = sarr[lb];
            float xwa = fmaf(inv, hwC[2 * e],     offs);
            float xwb = fmaf(inv, hwC[2 * e + 1], offs);
            a0 = fmaxf(a0, fmaf(pa.x - pi.x, wb0, fmaf(pa.y - pi.y, wb1, xwa)));
            a1 = fmaxf(a1, fmaf(pb.x - pi.x, wb0, fmaf(pb.y - pi.y, wb1, xwb)));
        }
        if (r + 1 < 32) {
#pragma unroll
            for (int e = 0; e < 5; ++e) {
                int ja = base + (int)(idx1[e] & 0xFFFFu);
                int jb = base + (int)(idx1[e] >> 16);
                hwN[2 * e]     = hw[(size_t)ja * HID + lane];
                hwN[2 * e + 1] = hw[(size_t)jb * HID + lane];
            }
            hwSN = hw[(size_t)(i + 1) * HID + lane];
        }
        float v = fmaxf(fmaxf(a0, a1), 0.f);
        cs += v; ss = fmaf(v, v, ss);
        vbuf[w][r * 68 + lane] = v;
#pragma unroll
        for (int e = 0; e < 5; ++e) idx0[e] = idx1[e];
        if (r + 2 < 32) {
#pragma unroll
            for (int e = 0; e < 5; ++e) idx1[e] = idx2[e];
        }
#pragma unroll
        for (int e = 0; e < KNNK; ++e) hwC[e] = hwN[e];
        hwS = hwSN;
    }
    v8bf bhi[4][2], blo[4][2];
    build_bfrags(Wna, lane, bhi, blo);
    mfma_gemm_store(vbuf[w], bhi, blo, lane, i0, out);

    red[tid] = cs; __syncthreads();
    if (tid < 64) atomicAdd(&stout[tid], red[tid] + red[tid + 64] + red[tid + 128] + red[tid + 192]);
#pragma unroll
    for (int o = 32; o > 0; o >>= 1) ss += __shfl_xor(ss, o, 64);
    __syncthreads();
    if (lane == 0) red[w] = ss;
    __syncthreads();
    if (tid == 0) atomicAdd(&stout[64], red[0] + red[1] + red[2] + red[3]);
}

// ---------------------------------------------------------------------------
// convB3: R16 1-deep pipeline + LDS pos + split fmax; no gemm, no global
// write — stats(h3) + per-graph col max.
// ---------------------------------------------------------------------------
__global__ __launch_bounds__(256, 2) void convB3_kernel(const float2* __restrict__ spos,
        const unsigned short* __restrict__ knn, const float* __restrict__ hw,
        const float* __restrict__ Wb, const float* __restrict__ stin,
        float* __restrict__ stout, float* __restrict__ gmax)
{
    __shared__ float red[256];
    __shared__ float2 sarr[NPG];
    const int tid  = threadIdx.x;
    const int lane = tid & 63, w = tid >> 6;
    const int wg   = WSWZ();
    const int i0   = wg * 128 + w * 32;
    const int base = (wg >> 4) << 11;
    const float wb0 = Wb[lane], wb1 = Wb[HID + lane];
    const float inv = stin[66], offs = stin[192 + lane];
    for (int t = tid; t < NPG; t += 256) sarr[t] = spos[base + t];
    __syncthreads();

    const unsigned* kb = (const unsigned*)knn;
    unsigned idx0[5], idx1[5];
    float hwC[KNNK], hwN[KNNK], hwS, hwSN;
#pragma unroll
    for (int e = 0; e < 5; ++e) idx0[e] = kb[(size_t)i0 * 5 + e];
#pragma unroll
    for (int e = 0; e < 5; ++e) idx1[e] = kb[(size_t)(i0 + 1) * 5 + e];
#pragma unroll
    for (int e = 0; e < 5; ++e) {
        int ja = base + (int)(idx0[e] & 0xFFFFu);
        int jb = base + (int)(idx0[e] >> 16);
        hwC[2 * e]     = hw[(size_t)ja * HID + lane];
        hwC[2 * e + 1] = hw[(size_t)jb * HID + lane];
    }
    hwS = hw[(size_t)i0 * HID + lane];

    float cs = 0.f, ss = 0.f, gm = 0.f;
    for (int r = 0; r < 32; ++r) {
        const int i = i0 + r;
        const int il = i - base;
        unsigned idx2[5];
        if (r + 2 < 32) {
#pragma unroll
            for (int e = 0; e < 5; ++e) idx2[e] = kb[(size_t)(i + 2) * 5 + e];
        }
        float2 pi = sarr[il];
        float a0 = fmaf(inv, hwS, offs);
        float a1 = -INFINITY;
#pragma unroll
        for (int e = 0; e < 5; ++e) {
            int la = (int)(idx0[e] & 0xFFFFu);
            int lb = (int)(idx0[e] >> 16);
            float2 pa = sarr[la];
            float2 pb = sarr[lb];
            float xwa = fmaf(inv, hwC[2 * e],     offs);
            float xwb = fmaf(inv, hwC[2 * e + 1], offs);
            a0 = fmaxf(a0, fmaf(pa.x - pi.x, wb0, fmaf(pa.y - pi.y, wb1, xwa)));
            a1 = fmaxf(a1, fmaf(pb.x - pi.x, wb0, fmaf(pb.y - pi.y, wb1, xwb)));
        }
        if (r + 1 < 32) {
#pragma unroll
            for (int e = 0; e < 5; ++e) {
                int ja = base + (int)(idx1[e] & 0xFFFFu);
                int jb = base + (int)(idx1[e] >> 16);
                hwN[2 * e]     = hw[(size_t)ja * HID + lane];
                hwN[2 * e + 1] = hw[(size_t)jb * HID + lane];
            }
            hwSN = hw[(size_t)(i + 1) * HID + lane];
        }
        float v = fmaxf(fmaxf(a0, a1), 0.f);
        cs += v; ss = fmaf(v, v, ss);
        gm = fmaxf(gm, v);
#pragma unroll
        for (int e = 0; e < 5; ++e) idx0[e] = idx1[e];
        if (r + 2 < 32) {
#pragma unroll
            for (int e = 0; e < 5; ++e) idx1[e] = idx2[e];
        }
#pragma unroll
        for (int e = 0; e < KNNK; ++e) hwC[e] = hwN[e];
        hwS = hwSN;
    }
    red[tid] = cs; __syncthreads();
    if (tid < 64) atomicAdd(&stout[tid], red[tid] + red[tid + 64] + red[tid + 128] + red[tid + 192]);
#pragma unroll
    for (int o = 32; o > 0; o >>= 1) ss += __shfl_xor(ss, o, 64);
    __syncthreads();
    if (lane == 0) red[w] = ss;
    __syncthreads();
    if (tid == 0) atomicAdd(&stout[64], red[0] + red[1] + red[2] + red[3]);
    const int g = (wg >> 4);
    atomicMax((int*)gmax + g * HID + lane, __float_as_int(gm));   // v >= 0
}

// ---------------------------------------------------------------------------
// head: normalize per-graph max, then 64->64 relu -> 64->2.
// ---------------------------------------------------------------------------
__global__ __launch_bounds__(64) void head_kernel(const float* __restrict__ gmax,
        const float* __restrict__ st3, const float* __restrict__ Wl1,
        const float* __restrict__ bl1, const float* __restrict__ Wl2,
        const float* __restrict__ bl2, float* __restrict__ out)
{
    const int b = blockIdx.x, c = threadIdx.x;
    float gv = (gmax[b * HID + c] - st3[128 + c]) * st3[66];
    float a = bl1[c];
#pragma unroll
    for (int k = 0; k < HID; ++k) a = fmaf(rdlane(gv, k), Wl1[k * HID + c], a);
    float h1 = fmaxf(a, 0.f);
    float o = bl2[c & 1];
#pragma unroll
    for (int k = 0; k < HID; ++k) o = fmaf(rdlane(h1, k), Wl2[k * 2 + (c & 1)], o);
    if (c < 2) out[b * 2 + c] = o;
}

// ---------------------------------------------------------------------------
extern "C" void kernel_launch(void* const* d_in, const int* in_sizes, int n_in,
                              void* d_out, int out_size, void* d_ws, size_t ws_size,
                              hipStream_t stream)
{
    const float2* pos = (const float2*)d_in[0];
    const float* W1  = (const float*)d_in[2];
    const float* b1  = (const float*)d_in[3];
    const float* W2  = (const float*)d_in[4];   // [66,64]
    const float* b2  = (const float*)d_in[5];
    const float* W3  = (const float*)d_in[6];   // [66,64]
    const float* b3  = (const float*)d_in[7];
    const float* Wl1 = (const float*)d_in[8];
    const float* bl1 = (const float*)d_in[9];
    const float* Wl2 = (const float*)d_in[10];
    const float* bl2 = (const float*)d_in[11];
    float* out = (float*)d_out;

    // workspace layout (~71.1 MB)
    char* p = (char*)d_ws;
    unsigned short* knn  = (unsigned short*)p;  p += (size_t)NTOT * KNNK * 2;  // 2.62 MB
    float2* spos = (float2*)p;                  p += (size_t)NTOT * 8;         // 1.05 MB
    unsigned short* y2xg = (unsigned short*)p;  p += (size_t)NTOT * 2;         // 0.26 MB
    float* bufA  = (float*)p;                   p += (size_t)NTOT * HID * 4;   // 33.55 MB
    float* bufB  = (float*)p;                   p += (size_t)NTOT * HID * 4;   // 33.55 MB
    float* st    = (float*)p;                   // 768 floats stats + 4096 gmax
    float* gmax  = st + 768;

    hipMemsetAsync(st, 0, (768 + NB * HID) * sizeof(float), stream);

    sort_kernel<<<NB, 1024, 0, stream>>>(pos, spos, y2xg);
    knn_kernel <<<NTOT / 128, 256, 0, stream>>>(spos, y2xg, knn);

    // layer 1 (writes h1 @ W2a via MFMA)
    conv1_kernel<<<NTOT / 128, 256, 0, stream>>>(spos, knn, W1, b1, W2, bufA, st);
    stats_kernel<<<1, 64, 0, stream>>>(st, W2, b2);

    // layer 2 (reads h1W2a, writes h2 @ W3a via MFMA)
    convG2_kernel<<<NTOT / 128, 256, 0, stream>>>(spos, knn, bufA, W2 + 64 * HID,
                                                  W3, st, bufB, st + 256);
    stats_kernel<<<1, 64, 0, stream>>>(st + 256, W3, b3);

    // layer 3 (reads h2W3a; no write — stats + per-graph max only)
    convB3_kernel<<<NTOT / 128, 256, 0, stream>>>(spos, knn, bufB, W3 + 64 * HID,
                                                  st + 256, st + 512, gmax);
    stats_kernel<<<1, 64, 0, stream>>>(st + 512, nullptr, nullptr);

    // head
    head_kernel<<<NB, 64, 0, stream>>>(gmax, st + 512, Wl1, bl1, Wl2, bl2, out);
}

// Round 18
// 282.637 us; speedup vs baseline: 1.0074x; 1.0074x over previous
//
#include <hip/hip_runtime.h>
#include <math.h>

#define NTOT   131072        // B * NPG
#define NPG    2048
#define NB     64
#define KNNK   10
#define HID    64
#define EPSPN  1e-5f

__device__ inline float rdlane(float v, int l) {
    return __int_as_float(__builtin_amdgcn_readlane(__float_as_int(v), l));
}

typedef short v8bf  __attribute__((ext_vector_type(8)));   // 8 bf16 = 4 VGPRs
typedef float v16f  __attribute__((ext_vector_type(16)));  // MFMA 32x32 acc

__device__ inline unsigned short f2bf(float f) {           // RNE f32->bf16
    unsigned u = __float_as_uint(f);
    return (unsigned short)((u + 0x7FFFu + ((u >> 16) & 1u)) >> 16);
}
__device__ inline float bf2f(unsigned short s) {
    return __uint_as_float((unsigned)s << 16);
}
__device__ inline void split_bf(float v, short& hi, short& lo) {
    unsigned short h = f2bf(v);
    hi = (short)h;
    lo = (short)f2bf(v - bf2f(h));
}

// ---------------------------------------------------------------------------
// sort: per graph, bitonic sort by x -> spos, then bitonic sort of the
// x-sorted array by y -> y2x map. (R12-proven)
// ---------------------------------------------------------------------------
__global__ __launch_bounds__(1024) void sort_kernel(const float2* __restrict__ pos,
        float2* __restrict__ spos, unsigned short* __restrict__ y2xg)
{
    __shared__ float2   sp[NPG];
    __shared__ unsigned sk[NPG];
    __shared__ unsigned sv[NPG];
    const int base = blockIdx.x * NPG;
    const int tid  = threadIdx.x;

    for (int t = tid; t < NPG; t += 1024) {
        unsigned u = __float_as_uint(pos[base + t].x);
        sk[t] = (u & 0x80000000u) ? ~u : (u | 0x80000000u);
        sv[t] = (unsigned)t;
    }
    __syncthreads();
    for (int k = 2; k <= NPG; k <<= 1) {
        for (int j = k >> 1; j > 0; j >>= 1) {
            int i = ((tid & ~(j - 1)) << 1) | (tid & (j - 1));
            int l = i + j;
            bool up = ((i & k) == 0);
            unsigned a = sk[i], b = sk[l];
            if ((a > b) == up) {
                sk[i] = b; sk[l] = a;
                unsigned t2 = sv[i]; sv[i] = sv[l]; sv[l] = t2;
            }
            __syncthreads();
        }
    }
    for (int t = tid; t < NPG; t += 1024) sp[t] = pos[base + sv[t]];
    __syncthreads();
    for (int t = tid; t < NPG; t += 1024) spos[base + t] = sp[t];

    for (int t = tid; t < NPG; t += 1024) {
        unsigned u = __float_as_uint(sp[t].y);
        sk[t] = (u & 0x80000000u) ? ~u : (u | 0x80000000u);
        sv[t] = (unsigned)t;                 // val = x-rank
    }
    __syncthreads();
    for (int k = 2; k <= NPG; k <<= 1) {
        for (int j = k >> 1; j > 0; j >>= 1) {
            int i = ((tid & ~(j - 1)) << 1) | (tid & (j - 1));
            int l = i + j;
            bool up = ((i & k) == 0);
            unsigned a = sk[i], b = sk[l];
            if ((a > b) == up) {
                sk[i] = b; sk[l] = a;
                unsigned t2 = sv[i]; sv[i] = sv[l]; sv[l] = t2;
            }
            __syncthreads();
        }
    }
    for (int t = tid; t < NPG; t += 1024) y2xg[base + t] = (unsigned short)sv[t];
}

// ---------------------------------------------------------------------------
// knn: R12-proven (91us): 2 lanes/query, single x-sorted pos array + u16
// rank maps (24KB LDS), batch-4 clamped candidates, pair prune threshold,
// bitonic pair-merge. Single combined insert ballot (R17's per-candidate
// ballots regressed: ballot overhead > ladder savings).
// ---------------------------------------------------------------------------
#define INSERT(INS, D2, JJ) do {                                              \
    const bool ins_ = (INS);                                                  \
    bd[9] = ins_ ? (D2) : bd[9];                                              \
    bi[9] = ins_ ? (JJ) : bi[9];                                              \
    _Pragma("unroll")                                                         \
    for (int kk = 0; kk < 9; ++kk) {                                          \
        bool sw_ = bd[kk] > bd[9];                                            \
        float tv_ = bd[kk]; int ti_ = bi[kk];                                 \
        bd[kk] = sw_ ? bd[9] : bd[kk]; bi[kk] = sw_ ? bi[9] : bi[kk];         \
        bd[9]  = sw_ ? tv_  : bd[9];   bi[9]  = sw_ ? ti_  : bi[9];           \
    }                                                                         \
} while (0)

#define CSWAP(A, B) do {                                                      \
    bool sw_ = bd[A] > bd[B];                                                 \
    float tf_ = bd[A]; int ti_ = bi[A];                                       \
    bd[A] = sw_ ? bd[B] : bd[A]; bi[A] = sw_ ? bi[B] : bi[A];                 \
    bd[B] = sw_ ? tf_  : bd[B]; bi[B] = sw_ ? ti_  : bi[B];                   \
} while (0)

__global__ __launch_bounds__(256) void knn_kernel(const float2* __restrict__ spos,
        const unsigned short* __restrict__ y2xg, unsigned short* __restrict__ knn)
{
    __shared__ float2 sarr[NPG];            // x-sorted positions (16KB)
    __shared__ unsigned short y2x[NPG];     // y-rank -> x-rank (4KB)
    __shared__ unsigned short x2y[NPG];     // x-rank -> y-rank (4KB)
    const int tid  = threadIdx.x;
    const int g    = blockIdx.x >> 4;
    const int base = g * NPG;

    for (int t = tid; t < NPG; t += 256) {
        sarr[t] = spos[base + t];
        y2x[t]  = y2xg[base + t];
    }
    __syncthreads();
    for (int t = tid; t < NPG; t += 256) {
        x2y[(int)y2x[t]] = (unsigned short)t;
    }
    __syncthreads();

    const int ql = ((blockIdx.x & 15) << 7) + (tid >> 1);   // query x-rank
    const int d  = tid & 1;
    const float qx = sarr[ql].x, qy = sarr[ql].y;
    const int py = (int)x2y[ql];

    float span_x = sarr[min(ql + 8, NPG - 1)].x - sarr[max(ql - 8, 0)].x;
    float span_y = sarr[(int)y2x[min(py + 8, NPG - 1)]].y
                 - sarr[(int)y2x[max(py - 8, 0)]].y;
    const bool cy   = span_y > span_x;
    const int  r    = cy ? py : ql;
    const int  limit = d ? (NPG - 1 - r) : r;
    const int  sign  = d ? 1 : -1;

    float bd[KNNK];
    int   bi[KNNK];
#pragma unroll
    for (int k = 0; k < KNNK; ++k) { bd[k] = INFINITY; bi[k] = 0; }

    int s = 1;
    bool alive = (limit >= 1);
    while (__any(alive)) {
        int j0 = min(NPG - 1, max(0, r + sign * s));
        int j1 = min(NPG - 1, max(0, r + sign * (s + 1)));
        int j2 = min(NPG - 1, max(0, r + sign * (s + 2)));
        int j3 = min(NPG - 1, max(0, r + sign * (s + 3)));
        int x0 = cy ? (int)y2x[j0] : j0;
        int x1 = cy ? (int)y2x[j1] : j1;
        int x2 = cy ? (int)y2x[j2] : j2;
        int x3 = cy ? (int)y2x[j3] : j3;
        float2 p0 = sarr[x0];
        float2 p1 = sarr[x1];
        float2 p2 = sarr[x2];
        float2 p3 = sarr[x3];
        float dx0 = __fsub_rn(qx, p0.x), dy0 = __fsub_rn(qy, p0.y);
        float dx1 = __fsub_rn(qx, p1.x), dy1 = __fsub_rn(qy, p1.y);
        float dx2 = __fsub_rn(qx, p2.x), dy2 = __fsub_rn(qy, p2.y);
        float dx3 = __fsub_rn(qx, p3.x), dy3 = __fsub_rn(qy, p3.y);
        float xs0 = __fmul_rn(dx0, dx0), ys0 = __fmul_rn(dy0, dy0);
        float xs1 = __fmul_rn(dx1, dx1), ys1 = __fmul_rn(dy1, dy1);
        float xs2 = __fmul_rn(dx2, dx2), ys2 = __fmul_rn(dy2, dy2);
        float xs3 = __fmul_rn(dx3, dx3), ys3 = __fmul_rn(dy3, dy3);
        float d20 = __fadd_rn(xs0, ys0);
        float d21 = __fadd_rn(xs1, ys1);
        float d22 = __fadd_rn(xs2, ys2);
        float d23 = __fadd_rn(xs3, ys3);
        bool v0 = alive && (s     <= limit);
        bool v1 = alive && (s + 1 <= limit);
        bool v2 = alive && (s + 2 <= limit);
        bool v3 = alive && (s + 3 <= limit);
        bool pre = (v0 && d20 < bd[9]) || (v1 && d21 < bd[9]) ||
                   (v2 && d22 < bd[9]) || (v3 && d23 < bd[9]);
        if (__any(pre)) {
            INSERT(v0 && (d20 < bd[9]), d20, x0);
            INSERT(v1 && (d21 < bd[9]), d21, x1);
            INSERT(v2 && (d22 < bd[9]), d22, x2);
            INSERT(v3 && (d23 < bd[9]), d23, x3);
        }
        float thr = fminf(bd[9], __shfl_xor(bd[9], 1));
        float pr3 = cy ? ys3 : xs3;
        alive = alive && (s + 4 <= limit) && (pr3 < thr);
        s += 4;
    }

#pragma unroll
    for (int ph = 0; ph < 10; ++ph) {
        if ((ph & 1) == 0) { CSWAP(0,1); CSWAP(2,3); CSWAP(4,5); CSWAP(6,7); CSWAP(8,9); }
        else               { CSWAP(1,2); CSWAP(3,4); CSWAP(5,6); CSWAP(7,8); }
    }
    float obd[KNNK]; int obi[KNNK];
#pragma unroll
    for (int k = 0; k < KNNK; ++k) {
        obd[k] = __shfl_xor(bd[k], 1);
        obi[k] = __shfl_xor(bi[k], 1);
    }
    if (d == 0) {
        const int row = (base + ql) * KNNK;
#pragma unroll
        for (int k = 0; k < KNNK; ++k) {
            bool ta = bd[k] < obd[9 - k];
            int idx = ta ? bi[k] : obi[9 - k];     // local x-rank
            knn[row + k] = (unsigned short)idx;
        }
    }
}

// ---------------------------------------------------------------------------
// MFMA gemm epilogue (split-bf16, R8/R14-verified numerics).
// Layouts (32x32x16 bf16): A: lane holds A[l&31][8*(l>>5)+j];
// B: B[8*(l>>5)+j][l&31]; C/D: row=(reg&3)+8*(reg>>2)+4*(l>>5), col=l&31.
// ---------------------------------------------------------------------------
__device__ inline void build_bfrags(const float* __restrict__ Wa, int lane,
                                    v8bf (&bhi)[4][2], v8bf (&blo)[4][2])
{
    const int cl = lane & 31, kg = lane >> 5;
#pragma unroll
    for (int kt = 0; kt < 4; ++kt)
#pragma unroll
        for (int nt = 0; nt < 2; ++nt)
#pragma unroll
            for (int j = 0; j < 8; ++j) {
                float wv = Wa[(kt * 16 + kg * 8 + j) * HID + nt * 32 + cl];
                short h, l;
                split_bf(wv, h, l);
                bhi[kt][nt][j] = h; blo[kt][nt][j] = l;
            }
}

__device__ inline void mfma_gemm_store(const float* vrow,
        const v8bf (&bhi)[4][2], const v8bf (&blo)[4][2],
        int lane, int i0, float* __restrict__ out)
{
    const int cl = lane & 31, kg = lane >> 5;
    v16f acc0, acc1;
#pragma unroll
    for (int q = 0; q < 16; ++q) { acc0[q] = 0.f; acc1[q] = 0.f; }
#pragma unroll
    for (int kt = 0; kt < 4; ++kt) {
        const float4 f0 = *(const float4*)(vrow + cl * 68 + kt * 16 + kg * 8);
        const float4 f1 = *(const float4*)(vrow + cl * 68 + kt * 16 + kg * 8 + 4);
        v8bf ah, al;
        short h, l;
        split_bf(f0.x, h, l); ah[0] = h; al[0] = l;
        split_bf(f0.y, h, l); ah[1] = h; al[1] = l;
        split_bf(f0.z, h, l); ah[2] = h; al[2] = l;
        split_bf(f0.w, h, l); ah[3] = h; al[3] = l;
        split_bf(f1.x, h, l); ah[4] = h; al[4] = l;
        split_bf(f1.y, h, l); ah[5] = h; al[5] = l;
        split_bf(f1.z, h, l); ah[6] = h; al[6] = l;
        split_bf(f1.w, h, l); ah[7] = h; al[7] = l;
        acc0 = __builtin_amdgcn_mfma_f32_32x32x16_bf16(ah, bhi[kt][0], acc0, 0, 0, 0);
        acc0 = __builtin_amdgcn_mfma_f32_32x32x16_bf16(al, bhi[kt][0], acc0, 0, 0, 0);
        acc0 = __builtin_amdgcn_mfma_f32_32x32x16_bf16(ah, blo[kt][0], acc0, 0, 0, 0);
        acc1 = __builtin_amdgcn_mfma_f32_32x32x16_bf16(ah, bhi[kt][1], acc1, 0, 0, 0);
        acc1 = __builtin_amdgcn_mfma_f32_32x32x16_bf16(al, bhi[kt][1], acc1, 0, 0, 0);
        acc1 = __builtin_amdgcn_mfma_f32_32x32x16_bf16(ah, blo[kt][1], acc1, 0, 0, 0);
    }
#pragma unroll
    for (int reg = 0; reg < 16; ++reg) {
        int rowc = (reg & 3) + 8 * (reg >> 2) + 4 * kg;
        out[(size_t)(i0 + rowc) * HID + cl]      = acc0[reg];
        out[(size_t)(i0 + rowc) * HID + 32 + cl] = acc1[reg];
    }
}

// XCD-aware work swizzle for grid=1024 (8 whole graphs per XCD's L2).
#define WSWZ() (((blockIdx.x & 7) << 7) | (blockIdx.x >> 3))

// ---------------------------------------------------------------------------
// conv1: edge conv (pos from LDS, split fmax chain) + MFMA gemm(W2a)
// (b-frags built AFTER the loop) + fused PairNorm stats.
// ---------------------------------------------------------------------------
__global__ __launch_bounds__(256) void conv1_kernel(const float2* __restrict__ spos,
        const unsigned short* __restrict__ knn, const float* __restrict__ W1,
        const float* __restrict__ b1, const float* __restrict__ W2a,
        float* __restrict__ out, float* __restrict__ st)
{
    __shared__ float red[256];
    __shared__ float2 sarr[NPG];                       // 16KB
    __shared__ __align__(16) float vbuf[4][32 * 68];   // 34.8KB
    const int tid  = threadIdx.x;
    const int lane = tid & 63, w = tid >> 6;
    const int wg   = WSWZ();
    const int i0   = wg * 128 + w * 32;
    const int base = (wg >> 4) << 11;
    const int il0  = i0 - base;
    const float w0 = W1[lane], w1 = W1[HID + lane], bb = b1[lane];
    for (int t = tid; t < NPG; t += 256) sarr[t] = spos[base + t];
    __syncthreads();
    float cs = 0.f, ss = 0.f;
    for (int r = 0; r < 32; ++r) {
        const int il = il0 + r;
        float2 pi = sarr[il];
        float a0 = bb, a1 = bb;                      // self edge (rel = 0)
#pragma unroll
        for (int e = 0; e < 5; ++e) {
            int ja = (int)knn[(size_t)(base + il) * KNNK + 2 * e];
            int jb = (int)knn[(size_t)(base + il) * KNNK + 2 * e + 1];
            float2 pa = sarr[ja];
            float2 pb = sarr[jb];
            a0 = fmaxf(a0, fmaf(pa.x - pi.x, w0, fmaf(pa.y - pi.y, w1, bb)));
            a1 = fmaxf(a1, fmaf(pb.x - pi.x, w0, fmaf(pb.y - pi.y, w1, bb)));
        }
        float v = fmaxf(fmaxf(a0, a1), 0.f);
        cs += v; ss = fmaf(v, v, ss);
        vbuf[w][r * 68 + lane] = v;
    }
    v8bf bhi[4][2], blo[4][2];
    build_bfrags(W2a, lane, bhi, blo);
    mfma_gemm_store(vbuf[w], bhi, blo, lane, i0, out);

    red[tid] = cs; __syncthreads();
    if (tid < 64) atomicAdd(&st[tid], red[tid] + red[tid + 64] + red[tid + 128] + red[tid + 192]);
#pragma unroll
    for (int o = 32; o > 0; o >>= 1) ss += __shfl_xor(ss, o, 64);
    __syncthreads();
    if (lane == 0) red[w] = ss;
    __syncthreads();
    if (tid == 0) atomicAdd(&st[64], red[0] + red[1] + red[2] + red[3]);
}

// ---------------------------------------------------------------------------
// stats: mean, inv = 1/sqrt(eps + var-of-rows), offs = b_next - inv*mean@Wnext_a
// ---------------------------------------------------------------------------
__global__ __launch_bounds__(64) void stats_kernel(float* __restrict__ st,
        const float* __restrict__ Wn, const float* __restrict__ bn)
{
    const int c = threadIdx.x;
    float mean = st[c] * (1.0f / (float)NTOT);
    st[128 + c] = mean;
    float m2 = mean * mean;
#pragma unroll
    for (int o = 32; o > 0; o >>= 1) m2 += __shfl_xor(m2, o, 64);
    float s = (st[64] - (float)NTOT * m2) * (1.0f / (float)NTOT);
    s = fmaxf(s, 0.f);
    float inv = 1.0f / sqrtf(EPSPN + s);
    if (c == 0) st[66] = inv;
    if (Wn != nullptr) {
        float dot = 0.f;
#pragma unroll
        for (int k = 0; k < HID; ++k) dot = fmaf(rdlane(mean, k), Wn[k * HID + c], dot);
        st[192 + c] = bn[c] - inv * dot;
    }
}

// ---------------------------------------------------------------------------
// convG2: 1-deep pipelined gather conv (idx 2-ahead, hw 1-ahead) + LDS
// pos + self-hw prefetch + split fmax chain + MFMA gemm (frags after loop).
// ---------------------------------------------------------------------------
__global__ __launch_bounds__(256, 2) void convG2_kernel(const float2* __restrict__ spos,
        const unsigned short* __restrict__ knn, const float* __restrict__ hw,
        const float* __restrict__ Wb, const float* __restrict__ Wna,
        const float* __restrict__ stin, float* __restrict__ out,
        float* __restrict__ stout)
{
    __shared__ float red[256];
    __shared__ float2 sarr[NPG];
    __shared__ __align__(16) float vbuf[4][32 * 68];
    const int tid  = threadIdx.x;
    const int lane = tid & 63, w = tid >> 6;
    const int wg   = WSWZ();
    const int i0   = wg * 128 + w * 32;
    const int base = (wg >> 4) << 11;
    const float wb0 = Wb[lane], wb1 = Wb[HID + lane];
    const float inv = stin[66], offs = stin[192 + lane];
    for (int t = tid; t < NPG; t += 256) sarr[t] = spos[base + t];
    __syncthreads();

    const unsigned* kb = (const unsigned*)knn;
    unsigned idx0[5], idx1[5];
    float hwC[KNNK], hwN[KNNK], hwS, hwSN;
#pragma unroll
    for (int e = 0; e < 5; ++e) idx0[e] = kb[(size_t)i0 * 5 + e];
#pragma unroll
    for (int e = 0; e < 5; ++e) idx1[e] = kb[(size_t)(i0 + 1) * 5 + e];
#pragma unroll
    for (int e = 0; e < 5; ++e) {
        int ja = base + (int)(idx0[e] & 0xFFFFu);
        int jb = base + (int)(idx0[e] >> 16);
        hwC[2 * e]     = hw[(size_t)ja * HID + lane];
        hwC[2 * e + 1] = hw[(size_t)jb * HID + lane];
    }
    hwS = hw[(size_t)i0 * HID + lane];

    float cs = 0.f, ss = 0.f;
    for (int r = 0; r < 32; ++r) {
        const int i = i0 + r;
        const int il = i - base;
        unsigned idx2[5];
        if (r + 2 < 32) {
#pragma unroll
            for (int e = 0; e < 5; ++e) idx2[e] = kb[(size_t)(i + 2) * 5 + e];
        }
        float2 pi = sarr[il];
        float a0 = fmaf(inv, hwS, offs);             // self edge (prefetched)
        float a1 = -INFINITY;
#pragma unroll
        for (int e = 0; e < 5; ++e) {
            int la = (int)(idx0[e] & 0xFFFFu);
            int lb = (int)(idx0[e] >> 16);
            float2 pa = sarr[la];
            float2 pb = sarr[lb];
            float xwa = fmaf(inv, hwC[2 * e],     offs);
            float xwb = fmaf(inv, hwC[2 * e + 1], offs);
            a0 = fmaxf(a0, fmaf(pa.x - pi.x, wb0, fmaf(pa.y - pi.y, wb1, xwa)));
            a1 = fmaxf(a1, fmaf(pb.x - pi.x, wb0, fmaf(pb.y - pi.y, wb1, xwb)));
        }
        if (r + 1 < 32) {
#pragma unroll
            for (int e = 0; e < 5; ++e) {
                int ja = base + (int)(idx1[e] & 0xFFFFu);
                int jb = base + (int)(idx1[e] >> 16);
                hwN[2 * e]     = hw[(size_t)ja * HID + lane];
                hwN[2 * e + 1] = hw[(size_t)jb * HID + lane];
            }
            hwSN = hw[(size_t)(i + 1) * HID + lane];
        }
        float v = fmaxf(fmaxf(a0, a1), 0.f);
        cs += v; ss = fmaf(v, v, ss);
        vbuf[w][r * 68 + lane] = v;
#pragma unroll
        for (int e = 0; e < 5; ++e) idx0[e] = idx1[e];
        if (r + 2 < 32) {
#pragma unroll
            for (int e = 0; e < 5; ++e) idx1[e] = idx2[e];
        }
#pragma unroll
        for (int e = 0; e < KNNK; ++e) hwC[e] = hwN[e];
        hwS = hwSN;
    }
    v8bf bhi[4][2], blo[4][2];
    build_bfrags(Wna, lane, bhi, blo);
    mfma_gemm_store(vbuf[w], bhi, blo, lane, i0, out);

    red[tid] = cs; __syncthreads();
    if (tid < 64) atomicAdd(&stout[tid], red[tid] + red[tid + 64] + red[tid + 128] + red[tid + 192]);
#pragma unroll
    for (int o = 32; o > 0; o >>= 1) ss += __shfl_xor(ss, o, 64);
    __syncthreads();
    if (lane == 0) red[w] = ss;
    __syncthreads();
    if (tid == 0) atomicAdd(&stout[64], red[0] + red[1] + red[2] + red[3]);
}

// ---------------------------------------------------------------------------
// convB3: 1-deep pipeline + LDS pos + split fmax; no gemm, no global
// write — stats(h3) + per-graph col max.
// ---------------------------------------------------------------------------
__global__ __launch_bounds__(256, 2) void convB3_kernel(const float2* __restrict__ spos,
        const unsigned short* __restrict__ knn, const float* __restrict__ hw,
        const float* __restrict__ Wb, const float* __restrict__ stin,
        float* __restrict__ stout, float* __restrict__ gmax)
{
    __shared__ float red[256];
    __shared__ float2 sarr[NPG];
    const int tid  = threadIdx.x;
    const int lane = tid & 63, w = tid >> 6;
    const int wg   = WSWZ();
    const int i0   = wg * 128 + w * 32;
    const int base = (wg >> 4) << 11;
    const float wb0 = Wb[lane], wb1 = Wb[HID + lane];
    const float inv = stin[66], offs = stin[192 + lane];
    for (int t = tid; t < NPG; t += 256) sarr[t] = spos[base + t];
    __syncthreads();

    const unsigned* kb = (const unsigned*)knn;
    unsigned idx0[5], idx1[5];
    float hwC[KNNK], hwN[KNNK], hwS, hwSN;
#pragma unroll
    for (int e = 0; e < 5; ++e) idx0[e] = kb[(size_t)i0 * 5 + e];
#pragma unroll
    for (int e = 0; e < 5; ++e) idx1[e] = kb[(size_t)(i0 + 1) * 5 + e];
#pragma unroll
    for (int e = 0; e < 5; ++e) {
        int ja = base + (int)(idx0[e] & 0xFFFFu);
        int jb = base + (int)(idx0[e] >> 16);
        hwC[2 * e]     = hw[(size_t)ja * HID + lane];
        hwC[2 * e + 1] = hw[(size_t)jb * HID + lane];
    }
    hwS = hw[(size_t)i0 * HID + lane];

    float cs = 0.f, ss = 0.f, gm = 0.f;
    for (int r = 0; r < 32; ++r) {
        const int i = i0 + r;
        const int il = i - base;
        unsigned idx2[5];
        if (r + 2 < 32) {
#pragma unroll
            for (int e = 0; e < 5; ++e) idx2[e] = kb[(size_t)(i + 2) * 5 + e];
        }
        float2 pi = sarr[il];
        float a0 = fmaf(inv, hwS, offs);
        float a1 = -INFINITY;
#pragma unroll
        for (int e = 0; e < 5; ++e) {
            int la = (int)(idx0[e] & 0xFFFFu);
            int lb = (int)(idx0[e] >> 16);
            float2 pa = sarr[la];
            float2 pb = sarr[lb];
            float xwa = fmaf(inv, hwC[2 * e],     offs);
            float xwb = fmaf(inv, hwC[2 * e + 1], offs);
            a0 = fmaxf(a0, fmaf(pa.x - pi.x, wb0, fmaf(pa.y - pi.y, wb1, xwa)));
            a1 = fmaxf(a1, fmaf(pb.x - pi.x, wb0, fmaf(pb.y - pi.y, wb1, xwb)));
        }
        if (r + 1 < 32) {
#pragma unroll
            for (int e = 0; e < 5; ++e) {
                int ja = base + (int)(idx1[e] & 0xFFFFu);
                int jb = base + (int)(idx1[e] >> 16);
                hwN[2 * e]     = hw[(size_t)ja * HID + lane];
                hwN[2 * e + 1] = hw[(size_t)jb * HID + lane];
            }
            hwSN = hw[(size_t)(i + 1) * HID + lane];
        }
        float v = fmaxf(fmaxf(a0, a1), 0.f);
        cs += v; ss = fmaf(v, v, ss);
        gm = fmaxf(gm, v);
#pragma unroll
        for (int e = 0; e < 5; ++e) idx0[e] = idx1[e];
        if (r + 2 < 32) {
#pragma unroll
            for (int e = 0; e < 5; ++e) idx1[e] = idx2[e];
        }
#pragma unroll
        for (int e = 0; e < KNNK; ++e) hwC[e] = hwN[e];
        hwS = hwSN;
    }
    red[tid] = cs; __syncthreads();
    if (tid < 64) atomicAdd(&stout[tid], red[tid] + red[tid + 64] + red[tid + 128] + red[tid + 192]);
#pragma unroll
    for (int o = 32; o > 0; o >>= 1) ss += __shfl_xor(ss, o, 64);
    __syncthreads();
    if (lane == 0) red[w] = ss;
    __syncthreads();
    if (tid == 0) atomicAdd(&stout[64], red[0] + red[1] + red[2] + red[3]);
    const int g = (wg >> 4);
    atomicMax((int*)gmax + g * HID + lane, __float_as_int(gm));   // v >= 0
}

// ---------------------------------------------------------------------------
// head: normalize per-graph max, then 64->64 relu -> 64->2.
// ---------------------------------------------------------------------------
__global__ __launch_bounds__(64) void head_kernel(const float* __restrict__ gmax,
        const float* __restrict__ st3, const float* __restrict__ Wl1,
        const float* __restrict__ bl1, const float* __restrict__ Wl2,
        const float* __restrict__ bl2, float* __restrict__ out)
{
    const int b = blockIdx.x, c = threadIdx.x;
    float gv = (gmax[b * HID + c] - st3[128 + c]) * st3[66];
    float a = bl1[c];
#pragma unroll
    for (int k = 0; k < HID; ++k) a = fmaf(rdlane(gv, k), Wl1[k * HID + c], a);
    float h1 = fmaxf(a, 0.f);
    float o = bl2[c & 1];
#pragma unroll
    for (int k = 0; k < HID; ++k) o = fmaf(rdlane(h1, k), Wl2[k * 2 + (c & 1)], o);
    if (c < 2) out[b * 2 + c] = o;
}

// ---------------------------------------------------------------------------
extern "C" void kernel_launch(void* const* d_in, const int* in_sizes, int n_in,
                              void* d_out, int out_size, void* d_ws, size_t ws_size,
                              hipStream_t stream)
{
    const float2* pos = (const float2*)d_in[0];
    const float* W1  = (const float*)d_in[2];
    const float* b1  = (const float*)d_in[3];
    const float* W2  = (const float*)d_in[4];   // [66,64]
    const float* b2  = (const float*)d_in[5];
    const float* W3  = (const float*)d_in[6];   // [66,64]
    const float* b3  = (const float*)d_in[7];
    const float* Wl1 = (const float*)d_in[8];
    const float* bl1 = (const float*)d_in[9];
    const float* Wl2 = (const float*)d_in[10];
    const float* bl2 = (const float*)d_in[11];
    float* out = (float*)d_out;

    // workspace layout (~71.1 MB)
    char* p = (char*)d_ws;
    unsigned short* knn  = (unsigned short*)p;  p += (size_t)NTOT * KNNK * 2;  // 2.62 MB
    float2* spos = (float2*)p;                  p += (size_t)NTOT * 8;         // 1.05 MB
    unsigned short* y2xg = (unsigned short*)p;  p += (size_t)NTOT * 2;         // 0.26 MB
    float* bufA  = (float*)p;                   p += (size_t)NTOT * HID * 4;   // 33.55 MB
    float* bufB  = (float*)p;                   p += (size_t)NTOT * HID * 4;   // 33.55 MB
    float* st    = (float*)p;                   // 768 floats stats + 4096 gmax
    float* gmax  = st + 768;

    hipMemsetAsync(st, 0, (768 + NB * HID) * sizeof(float), stream);

    sort_kernel<<<NB, 1024, 0, stream>>>(pos, spos, y2xg);
    knn_kernel <<<NTOT / 128, 256, 0, stream>>>(spos, y2xg, knn);

    // layer 1 (writes h1 @ W2a via MFMA)
    conv1_kernel<<<NTOT / 128, 256, 0, stream>>>(spos, knn, W1, b1, W2, bufA, st);
    stats_kernel<<<1, 64, 0, stream>>>(st, W2, b2);

    // layer 2 (reads h1W2a, writes h2 @ W3a via MFMA)
    convG2_kernel<<<NTOT / 128, 256, 0, stream>>>(spos, knn, bufA, W2 + 64 * HID,
                                                  W3, st, bufB, st + 256);
    stats_kernel<<<1, 64, 0, stream>>>(st + 256, W3, b3);

    // layer 3 (reads h2W3a; no write — stats + per-graph max only)
    convB3_kernel<<<NTOT / 128, 256, 0, stream>>>(spos, knn, bufB, W3 + 64 * HID,
                                                  st + 256, st + 512, gmax);
    stats_kernel<<<1, 64, 0, stream>>>(st + 512, nullptr, nullptr);

    // head
    head_kernel<<<NB, 64, 0, stream>>>(gmax, st + 512, Wl1, bl1, Wl2, bl2, out);
}